// Round 8
// baseline (292.871 us; speedup 1.0000x reference)
//
#include <hip/hip_runtime.h>
#include <cstdint>
#include <cstddef>

#define BETA 5.5f
#define ALPHA 0.5f

constexpr int D   = 512;     // feature dim
constexpr int NB  = 4096;    // queries
constexpr int NK  = 16384;   // keys
constexpr int BQ  = 64;      // query tile per block
constexpr int BN  = 64;      // key chunk
constexpr int NSPLIT = 4;
constexpr int NRANGE = NK / NSPLIT;   // 4096
constexpr int CHUNKS = NRANGE / BN;   // 64
constexpr int KROW = D + 8;           // padded LDS row (bf16), 1040 B
constexpr int PROW = BN + 8;          // padded P row: 72

typedef __attribute__((ext_vector_type(8)))  short    short8;
typedef __attribute__((ext_vector_type(4)))  float    floatx4;
typedef __attribute__((ext_vector_type(4)))  uint32_t uint4v;
typedef __attribute__((ext_vector_type(2)))  uint32_t uint2v;

__device__ inline uint32_t f2bf1(float f) {
  union { float f; uint32_t u; } v; v.f = f;
  return (v.u + 0x7FFFu + ((v.u >> 16) & 1u)) >> 16;   // RNE
}
__device__ inline uint32_t pack2(float a, float b) {
  return f2bf1(a) | (f2bf1(b) << 16);
}
// HW packed f32->bf16 (RNE, same rounding as f2bf1): 1 op replaces ~10.
__device__ inline uint32_t cvt_pk_bf16(float lo, float hi) {
  uint32_t r;
  asm("v_cvt_pk_bf16_f32 %0, %1, %2" : "=v"(r) : "v"(lo), "v"(hi));
  return r;
}

__device__ inline void load_lds16(const void* g, void* l) {
  __builtin_amdgcn_global_load_lds(
      (const __attribute__((address_space(1))) uint32_t*)g,
      (__attribute__((address_space(3))) uint32_t*)l, 16, 0, 0);
}

// ---------------- normalize Q -> Qn (bf16), and init out = Q ----------------
__global__ void norm_q_kernel(const float* __restrict__ q,
                              float* __restrict__ out,
                              unsigned short* __restrict__ Qn) {
  const int wave = threadIdx.x >> 6, lane = threadIdx.x & 63;
  const int row = blockIdx.x * 4 + wave;
  const float4* qr = (const float4*)(q + (size_t)row * D);
  float4 a = qr[lane * 2];
  float4 b = qr[lane * 2 + 1];
  float ss = a.x*a.x + a.y*a.y + a.z*a.z + a.w*a.w
           + b.x*b.x + b.y*b.y + b.z*b.z + b.w*b.w;
#pragma unroll
  for (int m = 32; m >= 1; m >>= 1) ss += __shfl_xor(ss, m, 64);
  const float sc = 1.0f / fmaxf(sqrtf(ss), 1e-12f);
  float4* orow = (float4*)(out + (size_t)row * D);
  orow[lane * 2]     = a;
  orow[lane * 2 + 1] = b;
  uint4v w;
  w.x = pack2(a.x*sc, a.y*sc); w.y = pack2(a.z*sc, a.w*sc);
  w.z = pack2(b.x*sc, b.y*sc); w.w = pack2(b.z*sc, b.w*sc);
  *(uint4v*)(Qn + (size_t)row * D + lane * 8) = w;
}

// ------ normalize K -> Kn (bf16 row-major) + KnT (bf16 transposed) ----------
__global__ void norm_k_kernel(const float* __restrict__ k,
                              unsigned short* __restrict__ Kn,
                              unsigned short* __restrict__ KnT) {
  __shared__ unsigned short tile[64 * KROW];
  const int wave = threadIdx.x >> 6, lane = threadIdx.x & 63;
  const int n0 = blockIdx.x * 64;
#pragma unroll
  for (int i = 0; i < 4; ++i) {
    const int rl = wave * 4 + i;
    const int n  = n0 + rl;
    const float4* kr = (const float4*)(k + (size_t)n * D);
    float4 a = kr[lane * 2], b = kr[lane * 2 + 1];
    float ss = a.x*a.x + a.y*a.y + a.z*a.z + a.w*a.w
             + b.x*b.x + b.y*b.y + b.z*b.z + b.w*b.w;
#pragma unroll
    for (int m = 32; m >= 1; m >>= 1) ss += __shfl_xor(ss, m, 64);
    const float sc = 1.0f / fmaxf(sqrtf(ss), 1e-12f);
    uint4v w;
    w.x = pack2(a.x*sc, a.y*sc); w.y = pack2(a.z*sc, a.w*sc);
    w.z = pack2(b.x*sc, b.y*sc); w.w = pack2(b.z*sc, b.w*sc);
    *(uint4v*)(Kn + (size_t)n * D + lane * 8) = w;
    *(uint4v*)&tile[rl * KROW + lane * 8]     = w;
  }
  __syncthreads();
  const int dsub = threadIdx.x >> 3;        // 0..127
  const int nl   = (threadIdx.x & 7) * 8;   // 0..56
#pragma unroll
  for (int iter = 0; iter < 4; ++iter) {
    const int d = iter * 128 + dsub;
    uint4v w;
    w.x = (uint32_t)tile[(nl+0)*KROW + d] | ((uint32_t)tile[(nl+1)*KROW + d] << 16);
    w.y = (uint32_t)tile[(nl+2)*KROW + d] | ((uint32_t)tile[(nl+3)*KROW + d] << 16);
    w.z = (uint32_t)tile[(nl+4)*KROW + d] | ((uint32_t)tile[(nl+5)*KROW + d] << 16);
    w.w = (uint32_t)tile[(nl+6)*KROW + d] | ((uint32_t)tile[(nl+7)*KROW + d] << 16);
    *(uint4v*)(KnT + (size_t)d * NK + n0 + nl) = w;
  }
}

// ---------------- fused: S = Qn Kn^T chunk, P = exp, O += P Kn --------------
// v9 = R6 skeleton + three cuts to the S-wave critical chain (R7 proved the
// stall is intra-wave, not sync-mechanism):
//  1. split-K accumulators: 8 independent MFMA chains (even/odd kb) of depth
//     8 instead of 4 chains of 16 -> dep-latency covered by a 155-cy issue
//     window; summed before exp.
//  2. staging DMA moved to O-waves (the slack stream): S issues ZERO vm ops;
//     S region-end wait is lgkmcnt(0) only. Staging lead = 1 region
//     (~5000 cy >> DMA latency). Hazards: stage(r+1)->buf (r+1)&1 while S
//     reads buf r&1 (disjoint); every overwrite barrier-separated from the
//     last read; O's vmcnt(16) at region end drains stage, keeps ktf in
//     flight.
//  3. v_cvt_pk_bf16_f32 pack (same RNE rounding, ~70 fewer VALU on S chain).
// Region r: S computes S(r) from buf r&1 -> P slot r&1; O stages chunk r+1,
// consumes P(r-1) x ktf(r-1), loads ktf(r). O runs one extra tail region.
// Barriers: S = 1 + CHUNKS, O = 1 + CHUNKS. Matched.
__global__ __launch_bounds__(512, 2) void fused_kernel(
    const unsigned short* __restrict__ Qn,
    const unsigned short* __restrict__ Kn,
    const unsigned short* __restrict__ KnT,
    float* __restrict__ out) {
  __shared__ unsigned short K_lds[2][BN * KROW];   // 2 x 66.5 KB
  __shared__ unsigned short P_lds[2][BQ * PROW];   // 2 x 9.2 KB  (151.5 KB)

  const int tid  = threadIdx.x;
  const int wave = tid >> 6, lane = tid & 63;
  const int l15  = lane & 15, quad = lane >> 4;
  const int nsplit = blockIdx.x & (NSPLIT - 1);
  const int qtile  = blockIdx.x >> 2;           // 0..63
  const int q0     = qtile * BQ;
  const int nbase  = nsplit * NRANGE;

  if (wave < 4) {
    // ================= S-producer: GEMM1 + exp -> P_lds ===================
    const int qh = wave & 1, nh = wave >> 1;
    short8 qf[2][16];              // 32 q-cols x 512 k
    {
      const unsigned short* qrow0 = Qn + (size_t)(q0 + qh * 32 + l15) * D + quad * 8;
#pragma unroll
      for (int qt = 0; qt < 2; ++qt)
#pragma unroll
        for (int kb = 0; kb < 16; ++kb)
          qf[qt][kb] = *(const short8*)(qrow0 + (size_t)qt * 16 * D + kb * 32);
    }

    floatx4 sacc_e[2][2], sacc_o[2][2];   // 8 independent chains

    auto a_read8 = [&](int buf, int kb0, short8* af) {
#pragma unroll
      for (int i = 0; i < 4; ++i) {
        af[2*i]   = *(const short8*)&K_lds[buf][(nh*32 +      l15) * KROW + (kb0+i)*32 + quad*8];
        af[2*i+1] = *(const short8*)&K_lds[buf][(nh*32 + 16 + l15) * KROW + (kb0+i)*32 + quad*8];
      }
    };
    auto g1c = [&](const short8* af, int kb0) {
      __builtin_amdgcn_s_setprio(1);
#pragma unroll
      for (int i = 0; i < 4; ++i) {
        auto& sa = (i & 1) ? sacc_o : sacc_e;    // i compile-time (unrolled)
        sa[0][0] = __builtin_amdgcn_mfma_f32_16x16x32_bf16(af[2*i],   qf[0][kb0+i], sa[0][0], 0, 0, 0);
        sa[0][1] = __builtin_amdgcn_mfma_f32_16x16x32_bf16(af[2*i],   qf[1][kb0+i], sa[0][1], 0, 0, 0);
        sa[1][0] = __builtin_amdgcn_mfma_f32_16x16x32_bf16(af[2*i+1], qf[0][kb0+i], sa[1][0], 0, 0, 0);
        sa[1][1] = __builtin_amdgcn_mfma_f32_16x16x32_bf16(af[2*i+1], qf[1][kb0+i], sa[1][1], 0, 0, 0);
      }
      __builtin_amdgcn_s_setprio(0);
    };
    auto gemm1_region = [&](int buf) {
#pragma unroll
      for (int nt = 0; nt < 2; ++nt)
#pragma unroll
        for (int qt = 0; qt < 2; ++qt) {
          sacc_e[nt][qt] = (floatx4){0.f, 0.f, 0.f, 0.f};
          sacc_o[nt][qt] = (floatx4){0.f, 0.f, 0.f, 0.f};
        }
      short8 afA[8], afB[8];
      a_read8(buf, 0, afA);              // depth-2 operand pipeline
      a_read8(buf, 4, afB);
      g1c(afA, 0);
      a_read8(buf, 8, afA);
      g1c(afB, 4);
      a_read8(buf, 12, afB);
      g1c(afA, 8);
      g1c(afB, 12);
    };
    auto exp_pw = [&](int slot) {
#pragma unroll
      for (int qt = 0; qt < 2; ++qt)
#pragma unroll
        for (int nt = 0; nt < 2; ++nt) {
          const floatx4 s = sacc_e[nt][qt] + sacc_o[nt][qt];
          const float e0 = __expf(BETA * (s[0] - 1.f));
          const float e1 = __expf(BETA * (s[1] - 1.f));
          const float e2 = __expf(BETA * (s[2] - 1.f));
          const float e3 = __expf(BETA * (s[3] - 1.f));
          uint2v w;
          w.x = cvt_pk_bf16(e0, e1);
          w.y = cvt_pk_bf16(e2, e3);
          *(uint2v*)&P_lds[slot][(qh*32 + qt*16 + l15) * PROW + nh*32 + nt*16 + quad*4] = w;
        }
    };

    // prologue: wait own qf loads; B0 (O has staged chunk 0 by then)
    asm volatile("s_waitcnt vmcnt(0)" ::: "memory");
    asm volatile("s_barrier" ::: "memory");            // B0

#pragma unroll 1
    for (int r = 0; r < CHUNKS; ++r) {
      gemm1_region(r & 1);               // S(r) from buf r&1
      exp_pw(r & 1);                     // P(r) -> slot r&1
      asm volatile("s_waitcnt lgkmcnt(0)" ::: "memory");  // P visible
      asm volatile("s_barrier" ::: "memory");
    }
    // S exits; O runs its tail region (no barrier there)
  } else {
    // ========== O-consumer: staging DMA + GEMM2 + epilogue ================
    const int ow = wave - 4;               // 0..3
    floatx4 oacc[4][8] = {};               // 64q x 128d
    short8 ktf[2][8];                      // 64 reg
    const unsigned short* ktb = KnT + (size_t)(ow * 128 + l15) * NK + nbase + quad * 8;

    auto stage = [&](int ch, int buf) {
#pragma unroll
      for (int i = 0; i < 16; ++i) {
        const int row = ow * 16 + i;
        load_lds16(Kn + (size_t)(nbase + ch * BN + row) * D + lane * 8,
                   &K_lds[buf][row * KROW]);
      }
    };
    auto ldKT = [&](short8* kt, int c, int kb2) {
#pragma unroll
      for (int td = 0; td < 8; ++td)
        kt[td] = *(const short8*)(ktb + (size_t)td * 16 * NK + c * BN + kb2 * 32);
    };
    auto pf_read = [&](int slot, int kb2, short8* pf) {
#pragma unroll
      for (int tr = 0; tr < 4; ++tr)
        pf[tr] = *(const short8*)&P_lds[slot][(tr*16 + l15) * PROW + kb2*32 + quad*8];
    };
    auto g2c = [&](const short8* pf, const short8* kt) {
      __builtin_amdgcn_s_setprio(1);
#pragma unroll
      for (int td = 0; td < 8; ++td)
#pragma unroll
        for (int tr = 0; tr < 4; ++tr)
          oacc[tr][td] = __builtin_amdgcn_mfma_f32_16x16x32_bf16(
              pf[tr], kt[td], oacc[tr][td], 0, 0, 0);
      __builtin_amdgcn_s_setprio(0);
    };

    // prologue: stage chunk 0, drain, B0
    stage(0, 0);
    asm volatile("s_waitcnt vmcnt(0)" ::: "memory");
    asm volatile("s_barrier" ::: "memory");            // B0

#pragma unroll 1
    for (int r = 0; r < CHUNKS; ++r) {
      if (r + 1 < CHUNKS) stage(r + 1, (r + 1) & 1);   // S reads buf r&1: disjoint
      if (r >= 1) {
        short8 pf0[4], pf1[4];
        pf_read((r - 1) & 1, 0, pf0);    // P(r-1)
        pf_read((r - 1) & 1, 1, pf1);
        g2c(pf0, ktf[0]);                // ktf(r-1); compiler emits counted vmcnt
        ldKT(ktf[0], r, 0);              // refill -> chunk r (WAR after last use)
        g2c(pf1, ktf[1]);
        ldKT(ktf[1], r, 1);
      } else {
        ldKT(ktf[0], 0, 0);
        ldKT(ktf[1], 0, 1);
      }
      // drain stage(r+1) (oldest), keep ktf(r) (16 newest) in flight
      asm volatile("s_waitcnt vmcnt(16)" ::: "memory");
      asm volatile("s_barrier" ::: "memory");
    }
    // tail region: consume P(CHUNKS-1) x ktf(CHUNKS-1); no barrier
    {
      short8 pf0[4], pf1[4];
      pf_read((CHUNKS - 1) & 1, 0, pf0);
      pf_read((CHUNKS - 1) & 1, 1, pf1);
      g2c(pf0, ktf[0]);
      g2c(pf1, ktf[1]);
    }

    // ---- epilogue: out += ALPHA * O (out pre-init to Q) ----
    const int colbase = ow * 128 + l15;
#pragma unroll
    for (int tr = 0; tr < 4; ++tr)
#pragma unroll
      for (int td = 0; td < 8; ++td)
#pragma unroll
        for (int r4 = 0; r4 < 4; ++r4)
          atomicAdd(out + (size_t)(q0 + tr*16 + quad*4 + r4) * D + colbase + td*16,
                    ALPHA * oacc[tr][td][r4]);
  }
}

extern "C" void kernel_launch(void* const* d_in, const int* in_sizes, int n_in,
                              void* d_out, int out_size, void* d_ws, size_t ws_size,
                              hipStream_t stream) {
  (void)in_sizes; (void)n_in; (void)out_size; (void)ws_size;
  const float* q = (const float*)d_in[0];
  const float* k = (const float*)d_in[1];
  float* out = (float*)d_out;
  unsigned short* Qn  = (unsigned short*)d_ws;          //  4 MB
  unsigned short* Kn  = Qn + (size_t)NB * D;            // 16 MB
  unsigned short* KnT = Kn + (size_t)NK * D;            // 16 MB  (total 36 MB)

  hipLaunchKernelGGL(norm_q_kernel, dim3(NB / 4),  dim3(256),  0, stream, q, out, Qn);
  hipLaunchKernelGGL(norm_k_kernel, dim3(NK / 64), dim3(1024), 0, stream, k, Kn, KnT);
  hipLaunchKernelGGL(fused_kernel, dim3((NB / BQ) * NSPLIT), dim3(512), 0, stream,
                     Qn, Kn, KnT, out);
}

// Round 9
// 265.830 us; speedup vs baseline: 1.1017x; 1.1017x over previous
//
#include <hip/hip_runtime.h>
#include <cstdint>
#include <cstddef>

#define BETA 5.5f
#define ALPHA 0.5f

constexpr int D   = 512;     // feature dim
constexpr int NB  = 4096;    // queries
constexpr int NK  = 16384;   // keys
constexpr int BQ  = 64;      // query tile per block
constexpr int BN  = 64;      // key chunk
constexpr int NSPLIT = 4;
constexpr int NRANGE = NK / NSPLIT;   // 4096
constexpr int CHUNKS = NRANGE / BN;   // 64
constexpr int KROW = D + 8;           // padded LDS row (bf16), 1040 B
constexpr int PROW = BN + 8;          // padded P row: 72

typedef __attribute__((ext_vector_type(8)))  short    short8;
typedef __attribute__((ext_vector_type(4)))  float    floatx4;
typedef __attribute__((ext_vector_type(4)))  uint32_t uint4v;
typedef __attribute__((ext_vector_type(2)))  uint32_t uint2v;

__device__ inline uint32_t f2bf1(float f) {
  union { float f; uint32_t u; } v; v.f = f;
  return (v.u + 0x7FFFu + ((v.u >> 16) & 1u)) >> 16;   // RNE
}
__device__ inline uint32_t pack2(float a, float b) {
  return f2bf1(a) | (f2bf1(b) << 16);
}

__device__ inline void load_lds16(const void* g, void* l) {
  __builtin_amdgcn_global_load_lds(
      (const __attribute__((address_space(1))) uint32_t*)g,
      (__attribute__((address_space(3))) uint32_t*)l, 16, 0, 0);
}

// ---------------- normalize Q -> Qn (bf16), and init out = Q ----------------
__global__ void norm_q_kernel(const float* __restrict__ q,
                              float* __restrict__ out,
                              unsigned short* __restrict__ Qn) {
  const int wave = threadIdx.x >> 6, lane = threadIdx.x & 63;
  const int row = blockIdx.x * 4 + wave;
  const float4* qr = (const float4*)(q + (size_t)row * D);
  float4 a = qr[lane * 2];
  float4 b = qr[lane * 2 + 1];
  float ss = a.x*a.x + a.y*a.y + a.z*a.z + a.w*a.w
           + b.x*b.x + b.y*b.y + b.z*b.z + b.w*b.w;
#pragma unroll
  for (int m = 32; m >= 1; m >>= 1) ss += __shfl_xor(ss, m, 64);
  const float sc = 1.0f / fmaxf(sqrtf(ss), 1e-12f);
  float4* orow = (float4*)(out + (size_t)row * D);
  orow[lane * 2]     = a;
  orow[lane * 2 + 1] = b;
  uint4v w;
  w.x = pack2(a.x*sc, a.y*sc); w.y = pack2(a.z*sc, a.w*sc);
  w.z = pack2(b.x*sc, b.y*sc); w.w = pack2(b.z*sc, b.w*sc);
  *(uint4v*)(Qn + (size_t)row * D + lane * 8) = w;
}

// ------ normalize K -> Kn (bf16 row-major) + KnT (bf16 transposed) ----------
// Transpose-read rotation: KROW/2 = 260 dwords == 4 (mod 32), so the 8 lanes
// sharing dsub (nl steps of 8: 8*260 == 0 mod 32) hit ONE bank -> 8-way
// conflict on every u16 read. Rotating the column assignment per lane,
// d' = (dsub + nl) & 127, makes those lanes differ by 8*521 elems == 8
// (mod 64) -> dword banks b0+{0,4,...,28}: conflict-free. Coverage stays
// bijective per nl. Cost: KnT global writes become scattered 16B chunks.
__global__ void norm_k_kernel(const float* __restrict__ k,
                              unsigned short* __restrict__ Kn,
                              unsigned short* __restrict__ KnT) {
  __shared__ unsigned short tile[64 * KROW];
  const int wave = threadIdx.x >> 6, lane = threadIdx.x & 63;
  const int n0 = blockIdx.x * 64;
#pragma unroll
  for (int i = 0; i < 4; ++i) {
    const int rl = wave * 4 + i;
    const int n  = n0 + rl;
    const float4* kr = (const float4*)(k + (size_t)n * D);
    float4 a = kr[lane * 2], b = kr[lane * 2 + 1];
    float ss = a.x*a.x + a.y*a.y + a.z*a.z + a.w*a.w
             + b.x*b.x + b.y*b.y + b.z*b.z + b.w*b.w;
#pragma unroll
    for (int m = 32; m >= 1; m >>= 1) ss += __shfl_xor(ss, m, 64);
    const float sc = 1.0f / fmaxf(sqrtf(ss), 1e-12f);
    uint4v w;
    w.x = pack2(a.x*sc, a.y*sc); w.y = pack2(a.z*sc, a.w*sc);
    w.z = pack2(b.x*sc, b.y*sc); w.w = pack2(b.z*sc, b.w*sc);
    *(uint4v*)(Kn + (size_t)n * D + lane * 8) = w;
    *(uint4v*)&tile[rl * KROW + lane * 8]     = w;
  }
  __syncthreads();
  const int dsub = threadIdx.x >> 3;        // 0..127
  const int nl   = (threadIdx.x & 7) * 8;   // 0..56
#pragma unroll
  for (int iter = 0; iter < 4; ++iter) {
    const int d = iter * 128 + ((dsub + nl) & 127);   // rotated column
    uint4v w;
    w.x = (uint32_t)tile[(nl+0)*KROW + d] | ((uint32_t)tile[(nl+1)*KROW + d] << 16);
    w.y = (uint32_t)tile[(nl+2)*KROW + d] | ((uint32_t)tile[(nl+3)*KROW + d] << 16);
    w.z = (uint32_t)tile[(nl+4)*KROW + d] | ((uint32_t)tile[(nl+5)*KROW + d] << 16);
    w.w = (uint32_t)tile[(nl+6)*KROW + d] | ((uint32_t)tile[(nl+7)*KROW + d] << 16);
    *(uint4v*)(KnT + (size_t)d * NK + n0 + nl) = w;
  }
}

// ---------------- fused: S = Qn Kn^T chunk, P = exp, O += P Kn --------------
// v10 = R6 (best, 199us) + three isolated edits:
//  (a) S-waves hold setprio(1) for the whole branch, O-waves prio 0:
//      S is the measured long pole (O idles waiting on P); symmetric
//      per-cluster boosting gave the arbiter nothing to choose.
//  (b) S region order: operand ds_reads issued BEFORE the 16 staging-DMA
//      issues + their address VALU (was delaying the post-barrier operand
//      refill on the critical chain by ~100-200 cy/region).
//  (c) pack2 restored (hand cvt_pk asm was R8's regression, cf. m240),
//      single 4-chain sacc restored.
__global__ __launch_bounds__(512, 2) void fused_kernel(
    const unsigned short* __restrict__ Qn,
    const unsigned short* __restrict__ Kn,
    const unsigned short* __restrict__ KnT,
    float* __restrict__ out) {
  __shared__ unsigned short K_lds[2][BN * KROW];   // 2 x 66.5 KB
  __shared__ unsigned short P_lds[2][BQ * PROW];   // 2 x 9.2 KB  (151.5 KB)

  const int tid  = threadIdx.x;
  const int wave = tid >> 6, lane = tid & 63;
  const int l15  = lane & 15, quad = lane >> 4;
  const int nsplit = blockIdx.x & (NSPLIT - 1);
  const int qtile  = blockIdx.x >> 2;           // 0..63
  const int q0     = qtile * BQ;
  const int nbase  = nsplit * NRANGE;

  if (wave < 4) {
    // ================= S-producer: GEMM1 + exp -> P_lds ===================
    const int sw = wave;
    const int qh = wave & 1, nh = wave >> 1;
    short8 qf[2][16];              // 32 q-cols x all 512 k (persistent)
    {
      const unsigned short* qrow0 = Qn + (size_t)(q0 + qh * 32 + l15) * D + quad * 8;
#pragma unroll
      for (int qt = 0; qt < 2; ++qt)
#pragma unroll
        for (int kb = 0; kb < 16; ++kb)
          qf[qt][kb] = *(const short8*)(qrow0 + (size_t)qt * 16 * D + kb * 32);
    }

    floatx4 sacc[2][2];

    auto stage = [&](int ch, int buf) {
#pragma unroll
      for (int i = 0; i < 16; ++i) {
        const int row = sw * 16 + i;
        load_lds16(Kn + (size_t)(nbase + ch * BN + row) * D + lane * 8,
                   &K_lds[buf][row * KROW]);
      }
    };
    auto a_read8 = [&](int buf, int kb0, short8* af) {
#pragma unroll
      for (int i = 0; i < 4; ++i) {
        af[2*i]   = *(const short8*)&K_lds[buf][(nh*32 +      l15) * KROW + (kb0+i)*32 + quad*8];
        af[2*i+1] = *(const short8*)&K_lds[buf][(nh*32 + 16 + l15) * KROW + (kb0+i)*32 + quad*8];
      }
    };
    auto g1c = [&](const short8* af, int kb0) {
#pragma unroll
      for (int i = 0; i < 4; ++i) {
        sacc[0][0] = __builtin_amdgcn_mfma_f32_16x16x32_bf16(af[2*i],   qf[0][kb0+i], sacc[0][0], 0, 0, 0);
        sacc[0][1] = __builtin_amdgcn_mfma_f32_16x16x32_bf16(af[2*i],   qf[1][kb0+i], sacc[0][1], 0, 0, 0);
        sacc[1][0] = __builtin_amdgcn_mfma_f32_16x16x32_bf16(af[2*i+1], qf[0][kb0+i], sacc[1][0], 0, 0, 0);
        sacc[1][1] = __builtin_amdgcn_mfma_f32_16x16x32_bf16(af[2*i+1], qf[1][kb0+i], sacc[1][1], 0, 0, 0);
      }
    };
    // region body: operand reads FIRST, staging issue after (edit b)
    auto gemm1_region_st = [&](int buf, int sch, int sbuf, bool do_stage) {
#pragma unroll
      for (int nt = 0; nt < 2; ++nt)
#pragma unroll
        for (int qt = 0; qt < 2; ++qt) sacc[nt][qt] = (floatx4){0.f, 0.f, 0.f, 0.f};
      short8 afA[8], afB[8];
      a_read8(buf, 0, afA);              // critical-path reads first
      a_read8(buf, 4, afB);
      if (do_stage) stage(sch, sbuf);    // DMA issue after the reads
      g1c(afA, 0);
      a_read8(buf, 8, afA);
      g1c(afB, 4);
      a_read8(buf, 12, afB);
      g1c(afA, 8);
      g1c(afB, 12);
    };
    auto exp_pw = [&](int slot) {
#pragma unroll
      for (int qt = 0; qt < 2; ++qt)
#pragma unroll
        for (int nt = 0; nt < 2; ++nt) {
          const floatx4 s = sacc[nt][qt];
          uint2v w;
          w.x = pack2(__expf(BETA * (s[0] - 1.f)), __expf(BETA * (s[1] - 1.f)));
          w.y = pack2(__expf(BETA * (s[2] - 1.f)), __expf(BETA * (s[3] - 1.f)));
          *(uint2v*)&P_lds[slot][(qh*32 + qt*16 + l15) * PROW + nh*32 + nt*16 + quad*4] = w;
        }
    };

    __builtin_amdgcn_s_setprio(1);       // (edit a) producer priority, held

    // prologue
    stage(0, 0);
    asm volatile("s_waitcnt vmcnt(0)" ::: "memory");   // qf + stage(0) done
    asm volatile("s_barrier" ::: "memory");            // B0
    gemm1_region_st(0, 1, 1, true);                    // chunk 0, stage(1)
    exp_pw(0);
    asm volatile("s_waitcnt vmcnt(0) lgkmcnt(0)" ::: "memory"); // stage(1)+P(0)
    asm volatile("s_barrier" ::: "memory");            // B1

    // steady: region r computes chunk r+1 -> P_lds[(r+1)&1], stages r+2
#pragma unroll 1
    for (int r = 0; r + 2 < CHUNKS; ++r) {
      gemm1_region_st((r + 1) & 1, r + 2, r & 1, true);
      exp_pw((r + 1) & 1);
      asm volatile("s_waitcnt vmcnt(0) lgkmcnt(0)" ::: "memory");
      asm volatile("s_barrier" ::: "memory");
    }
    // tail: region CHUNKS-2 computes chunk CHUNKS-1 (no staging)
    gemm1_region_st((CHUNKS - 1) & 1, 0, 0, false);
    exp_pw((CHUNKS - 1) & 1);
    asm volatile("s_waitcnt lgkmcnt(0)" ::: "memory");
    asm volatile("s_barrier" ::: "memory");
    __builtin_amdgcn_s_setprio(0);
    // S-waves exit (O-waves' final region has no barrier)
  } else {
    // ================= O-consumer: GEMM2 + epilogue =======================
    const int w4 = wave - 4;               // d-slice [w4*128, +128)
    floatx4 oacc[4][8] = {};               // 64q x 128d
    short8 ktf[2][8];                      // 64 reg
    const unsigned short* ktb = KnT + (size_t)(w4 * 128 + l15) * NK + nbase + quad * 8;

    auto ldKT = [&](short8* kt, int c, int kb2) {
#pragma unroll
      for (int td = 0; td < 8; ++td)
        kt[td] = *(const short8*)(ktb + (size_t)td * 16 * NK + c * BN + kb2 * 32);
    };
    auto pf_read = [&](int slot, int kb2, short8* pf) {
#pragma unroll
      for (int tr = 0; tr < 4; ++tr)
        pf[tr] = *(const short8*)&P_lds[slot][(tr*16 + l15) * PROW + kb2*32 + quad*8];
    };
    auto g2c = [&](const short8* pf, const short8* kt) {
#pragma unroll
      for (int td = 0; td < 8; ++td)
#pragma unroll
        for (int tr = 0; tr < 4; ++tr)
          oacc[tr][td] = __builtin_amdgcn_mfma_f32_16x16x32_bf16(
              pf[tr], kt[td], oacc[tr][td], 0, 0, 0);
    };

    ldKT(ktf[0], 0, 0); ldKT(ktf[1], 0, 1);   // chunk 0 ktf in flight
    asm volatile("s_barrier" ::: "memory");    // B0
    asm volatile("s_barrier" ::: "memory");    // B1 (P(0) now visible)

    // steady: region r consumes P(r) x ktf(chunk r); issues ktf(r+1)
#pragma unroll 1
    for (int r = 0; r + 2 < CHUNKS; ++r) {
      short8 pf0[4], pf1[4];
      pf_read(r & 1, 0, pf0);            // both halves issued early
      pf_read(r & 1, 1, pf1);
      g2c(pf0, ktf[0]);                  // compiler waits vmcnt for ktf[0]
      ldKT(ktf[0], r + 1, 0);            // refill after last use (in-order WAR)
      g2c(pf1, ktf[1]);
      ldKT(ktf[1], r + 1, 1);
      asm volatile("s_barrier" ::: "memory");   // no waits: ktf stays in flight
    }
    // region CHUNKS-2: consume P(CHUNKS-2), issue ktf(CHUNKS-1)
    {
      const int r = CHUNKS - 2;
      short8 pf0[4], pf1[4];
      pf_read(r & 1, 0, pf0);
      pf_read(r & 1, 1, pf1);
      g2c(pf0, ktf[0]);
      ldKT(ktf[0], CHUNKS - 1, 0);
      g2c(pf1, ktf[1]);
      ldKT(ktf[1], CHUNKS - 1, 1);
      asm volatile("s_barrier" ::: "memory");
    }
    // final region: consume P(CHUNKS-1); no barrier
    {
      short8 pf0[4], pf1[4];
      pf_read((CHUNKS - 1) & 1, 0, pf0);
      pf_read((CHUNKS - 1) & 1, 1, pf1);
      g2c(pf0, ktf[0]);
      g2c(pf1, ktf[1]);
    }

    // ---- epilogue: out += ALPHA * O (out pre-init to Q) ----
    const int colbase = w4 * 128 + l15;
#pragma unroll
    for (int tr = 0; tr < 4; ++tr)
#pragma unroll
      for (int td = 0; td < 8; ++td)
#pragma unroll
        for (int r4 = 0; r4 < 4; ++r4)
          atomicAdd(out + (size_t)(q0 + tr*16 + quad*4 + r4) * D + colbase + td*16,
                    ALPHA * oacc[tr][td][r4]);
  }
}

extern "C" void kernel_launch(void* const* d_in, const int* in_sizes, int n_in,
                              void* d_out, int out_size, void* d_ws, size_t ws_size,
                              hipStream_t stream) {
  (void)in_sizes; (void)n_in; (void)out_size; (void)ws_size;
  const float* q = (const float*)d_in[0];
  const float* k = (const float*)d_in[1];
  float* out = (float*)d_out;
  unsigned short* Qn  = (unsigned short*)d_ws;          //  4 MB
  unsigned short* Kn  = Qn + (size_t)NB * D;            // 16 MB
  unsigned short* KnT = Kn + (size_t)NK * D;            // 16 MB  (total 36 MB)

  hipLaunchKernelGGL(norm_q_kernel, dim3(NB / 4),  dim3(256),  0, stream, q, out, Qn);
  hipLaunchKernelGGL(norm_k_kernel, dim3(NK / 64), dim3(1024), 0, stream, k, Kn, KnT);
  hipLaunchKernelGGL(fused_kernel, dim3((NB / BQ) * NSPLIT), dim3(512), 0, stream,
                     Qn, Kn, KnT, out);
}